// Round 10
// baseline (1740.566 us; speedup 1.0000x reference)
//
#include <hip/hip_runtime.h>
#include <math.h>

#define BATCH 1024
#define SEQ   256
#define UNITS 256
#define NC    128

typedef __attribute__((ext_vector_type(8))) short  short8;   // 8 bf16 = 4 regs
typedef __attribute__((ext_vector_type(4))) float  float4v;  // MFMA C/D
typedef unsigned long long u64;
typedef unsigned int       u32;

// Gate math (validated r1-r8: absmax <= 6.1e-5 vs 1.72e-4 threshold)
__device__ __forceinline__ float sigf(float x)  { return 1.f / (1.f + __expf(-x)); }
__device__ __forceinline__ float tanhf_(float x){ return 1.f - 2.f / (1.f + __expf(2.f * x)); }

__device__ __forceinline__ unsigned short bf16rne(float f) {
    unsigned u = __float_as_uint(f);
    return (unsigned short)((u + 0x7fffu + ((u >> 16) & 1u)) >> 16);
}
__device__ __forceinline__ float bf16tof(unsigned short s) {
    return __uint_as_float(((unsigned)s) << 16);
}

// ---------------------------------------------------------------------------
// prep: R0t/R1t[col][k] bf16 split (col = g*256+u, r4-verified layout);
//       Wkb[ch][u*4+g] = Wk + bias (gate-packed); H01A zeroed; ctr zeroed.
__global__ __launch_bounds__(256) void prep(
    const float* __restrict__ R, const float* __restrict__ Wk,
    const float* __restrict__ bias,
    unsigned short* __restrict__ R0t, unsigned short* __restrict__ R1t,
    float* __restrict__ Wkb, u32* __restrict__ H01A, u32* __restrict__ ctr)
{
    int i = blockIdx.x * 256 + threadIdx.x;    // 0..262143
    int col = i >> 8, k = i & 255;
    float v = R[k * 1024 + col];
    unsigned short r0 = bf16rne(v);
    R0t[i] = r0;
    R1t[i] = bf16rne(v - bf16tof(r0));
    H01A[i] = 0u;                              // h_0 = 0 (packed)
    if (i < NC * 1024) {
        int r = i & 1023;
        int u = r >> 2, g = r & 3;
        int src = (g << 8) + u;
        Wkb[i] = Wk[(i >> 10) * 1024 + src] + bias[src];
    }
    if (i < 1024) ctr[i] = 0u;                 // 64 rows x 16-u32 pad
}

// ---------------------------------------------------------------------------
// Persistent LSTM, two-row software pipeline (r9 structure; r10 fixes the
// MFMA->VALU hazard guard, which in r9 was a free-floating asm the compiler
// could legally schedule AFTER the epilogue's acc reads -> clipped low-order
// products -> 1.8e-4 absmax). Grid 128 x 256 thr (1 block/CU). Block =
// row-pair (2p,2p+1; 16 batches each) x 64 units. B-frags in 256 AGPRs
// (r8-validated). Phases alternate rows; the other row's poll + h-load MALL
// round-trip hides behind the current row's compute. Acyclic lockstep ->
// no deadlock; 128 blocks all resident.
__global__ __launch_bounds__(256, 1) void lstm_persist(
    const unsigned short* __restrict__ R0t, const unsigned short* __restrict__ R1t,
    const float* __restrict__ Wkb, const int* __restrict__ inp,
    u32* __restrict__ H01A, u32* __restrict__ H01B, u32* __restrict__ ctr)
{
    __shared__ u32 L[2][2][16 * 132];   // [rowSlot][plane][batch*132+col]

    const int tid  = threadIdx.x;
    const int lane = tid & 63;
    const int wv   = tid >> 6;                  // 0..3
    const int bI   = blockIdx.x;                // 0..127
    const int pr   = bI & 31;                   // pair index (pr%8 == bI%8)
    const int ui   = bI >> 5;                   // 0..3
    const int nl   = lane & 15;
    const int quad = lane >> 4;
    const int u    = ui * 64 + wv * 16 + nl;    // lane's unit
    const int row0 = pr << 1, row1 = row0 | 1;  // two 16-batch rows

    // B-frags (r4-verified layout) -> exactly 256 AGPRs, pinned (r8).
    short8 B0[4][8], B1[4][8];
#pragma unroll
    for (int g = 0; g < 4; g++)
#pragma unroll
        for (int kt = 0; kt < 8; kt++) {
            const int idx = ((g << 8) + u) * 256 + (kt << 5) + (quad << 3);
            B0[g][kt] = *(const short8*)&R0t[idx];
            B1[g][kt] = *(const short8*)&R1t[idx];
        }
#pragma unroll
    for (int g = 0; g < 4; g++)
#pragma unroll
        for (int kt = 0; kt < 8; kt++) {
            asm volatile("" : "+a"(B0[g][kt]));
            asm volatile("" : "+a"(B1[g][kt]));
        }

    float c[2][4] = {{0.f,0.f,0.f,0.f},{0.f,0.f,0.f,0.f}};

    // Preload row0/t=0 h (zeros) from H01A.
    u64 q[8];
    {
        const u64* src = (const u64*)(H01A + (row0 << 12));
#pragma unroll
        for (int i = 0; i < 8; i++)
            q[i] = __hip_atomic_load(src + tid + (i << 8), __ATOMIC_RELAXED,
                                     __HIP_MEMORY_SCOPE_AGENT);
    }

    for (int ph = 0; ph < 2 * SEQ; ph++) {
        const int t    = ph >> 1;
        const int cur  = ph & 1;
        const int rowC = cur ? row1 : row0;
        const int be   = (rowC << 4) + (quad << 2);   // lane's 4-batch base

        // inp gather for (rowC, t) — issued first, consumed in epilogue.
        int ch[4];
#pragma unroll
        for (int r = 0; r < 4; r++) ch[r] = inp[(be + r) * SEQ + t];

        // Unpack current row's h (loaded last phase) -> LDS planes.
#pragma unroll
        for (int i = 0; i < 8; i++) {
            const int e = tid + (i << 8);
            u32 w0 = (u32)q[i], w1 = (u32)(q[i] >> 32);
            const int rr = e >> 7, cp = e & 127;
            L[cur][0][rr * 132 + cp] = (w0 & 0xffffu) | (w1 << 16);
            L[cur][1][rr * 132 + cp] = (w0 >> 16) | (w1 & 0xffff0000u);
        }
        __syncthreads();

        // Poll other row's publish, then issue its h loads (in flight across
        // the rest of this phase -> latency hidden by compute below).
        {
            const int rowO = cur ? row0 : row1;
            const int tO   = cur ? t + 1 : t;
            if (tO < SEQ) {
                if (tO > 0) {
                    u32* poc = &ctr[rowO << 4];
                    const u32 target = (u32)(tO << 2);
                    while (__hip_atomic_load(poc, __ATOMIC_RELAXED,
                                             __HIP_MEMORY_SCOPE_AGENT) < target)
                        __builtin_amdgcn_s_sleep(1);
                }
                const u64* src = (const u64*)(((tO & 1) ? H01B : H01A) + (rowO << 12));
#pragma unroll
                for (int i = 0; i < 8; i++)
                    q[i] = __hip_atomic_load(src + tid + (i << 8), __ATOMIC_RELAXED,
                                             __HIP_MEMORY_SCOPE_AGENT);
            }
        }

        // Wkb gather (depends on ch; consumed in epilogue after MFMA block).
        float4v wk[4];
#pragma unroll
        for (int r = 0; r < 4; r++)
            wk[r] = *(const float4v*)&Wkb[(ch[r] << 10) + (u << 2)];

        // MFMA: A from LDS (shared by 4 waves), B from AGPRs. Full 4-product
        // split (a1*b1 restored for numerical margin; ~5% of phase budget).
        float4v acc[4];
#pragma unroll
        for (int kt = 0; kt < 8; kt++) {
            short8 a0 = *(const short8*)&L[cur][0][nl * 132 + (kt << 4) + (quad << 2)];
            short8 a1 = *(const short8*)&L[cur][1][nl * 132 + (kt << 4) + (quad << 2)];
            if (kt == 0) {
#pragma unroll
                for (int g = 0; g < 4; g++) {
                    asm volatile("v_mfma_f32_16x16x32_bf16 %0, %1, %2, 0"
                                 : "=v"(acc[g]) : "v"(a0), "a"(B0[g][0]));
                    asm volatile("v_mfma_f32_16x16x32_bf16 %0, %1, %2, %0"
                                 : "+v"(acc[g]) : "v"(a1), "a"(B0[g][0]));
                    asm volatile("v_mfma_f32_16x16x32_bf16 %0, %1, %2, %0"
                                 : "+v"(acc[g]) : "v"(a0), "a"(B1[g][0]));
                    asm volatile("v_mfma_f32_16x16x32_bf16 %0, %1, %2, %0"
                                 : "+v"(acc[g]) : "v"(a1), "a"(B1[g][0]));
                }
            } else {
#pragma unroll
                for (int g = 0; g < 4; g++) {
                    asm volatile("v_mfma_f32_16x16x32_bf16 %0, %1, %2, %0"
                                 : "+v"(acc[g]) : "v"(a0), "a"(B0[g][kt]));
                    asm volatile("v_mfma_f32_16x16x32_bf16 %0, %1, %2, %0"
                                 : "+v"(acc[g]) : "v"(a1), "a"(B0[g][kt]));
                    asm volatile("v_mfma_f32_16x16x32_bf16 %0, %1, %2, %0"
                                 : "+v"(acc[g]) : "v"(a0), "a"(B1[g][kt]));
                    asm volatile("v_mfma_f32_16x16x32_bf16 %0, %1, %2, %0"
                                 : "+v"(acc[g]) : "v"(a1), "a"(B1[g][kt]));
                }
            }
        }
        // Sound hazard barrier: acc is an OPERAND of the nop asm, so the
        // epilogue's acc reads cannot be scheduled before it, and it cannot
        // be scheduled before the MFMAs (r9's bug: free-floating nops).
        asm volatile("s_nop 7\n\ts_nop 7\n\ts_nop 7"
                     : "+v"(acc[0]), "+v"(acc[1]), "+v"(acc[2]), "+v"(acc[3]));

        // Epilogue: 4 (batch,unit) states per lane; h out packed u32.
        u32* Hout = (t & 1) ? H01A : H01B;
#pragma unroll
        for (int r = 0; r < 4; r++) {
            float zi = acc[0][r] + wk[r].x;
            float zf = acc[1][r] + wk[r].y;
            float zg = acc[2][r] + wk[r].z;
            float zo = acc[3][r] + wk[r].w;
            float ig = sigf(zi), fg = sigf(zf), gg = tanhf_(zg), og = sigf(zo);
            float cn = fg * c[cur][r] + ig * gg;
            c[cur][r] = cn;
            float hv = og * tanhf_(cn);
            unsigned short h0 = bf16rne(hv);
            unsigned short h1 = bf16rne(hv - bf16tof(h0));
            u32 packed = (u32)h0 | ((u32)h1 << 16);
            __hip_atomic_store(&Hout[(be + r) * 256 + u], packed,
                               __ATOMIC_RELAXED, __HIP_MEMORY_SCOPE_AGENT);
        }

        // Publish: syncthreads drains all waves' vmcnt (stores at coherence
        // point, r8-validated), then one RMW per block per row-step.
        if (t != SEQ - 1) {
            __syncthreads();
            if (tid == 0)
                __hip_atomic_fetch_add(&ctr[rowC << 4], 1u, __ATOMIC_RELAXED,
                                       __HIP_MEMORY_SCOPE_AGENT);
        }
    }
}

// ---------------------------------------------------------------------------
// logits = h_last @ dense_w + dense_b ; softmax. h unpacked = lo + hi bf16.
__global__ __launch_bounds__(128) void dense_softmax(
    const u32* __restrict__ H01, const float* __restrict__ W,
    const float* __restrict__ b, float* __restrict__ out)
{
    __shared__ float hsr[UNITS];
    __shared__ float red[NC];
    const int bq = blockIdx.x;
    const int n  = threadIdx.x;

    u32 v0 = H01[bq * 256 + n];
    u32 v1 = H01[bq * 256 + n + 128];
    hsr[n]       = bf16tof((unsigned short)(v0 & 0xffffu)) + bf16tof((unsigned short)(v0 >> 16));
    hsr[n + 128] = bf16tof((unsigned short)(v1 & 0xffffu)) + bf16tof((unsigned short)(v1 >> 16));
    __syncthreads();

    float acc = b[n];
#pragma unroll 8
    for (int k = 0; k < UNITS; k++) acc += hsr[k] * W[k * NC + n];

    red[n] = acc;
    __syncthreads();
    for (int s = 64; s > 0; s >>= 1) {
        if (n < s) red[n] = fmaxf(red[n], red[n + s]);
        __syncthreads();
    }
    float m = red[0];
    __syncthreads();

    float e = __expf(acc - m);
    red[n] = e;
    __syncthreads();
    for (int s = 64; s > 0; s >>= 1) {
        if (n < s) red[n] = red[n] + red[n + s];
        __syncthreads();
    }
    out[bq * NC + n] = e / red[0];
}

// ---------------------------------------------------------------------------
extern "C" void kernel_launch(void* const* d_in, const int* in_sizes, int n_in,
                              void* d_out, int out_size, void* d_ws, size_t ws_size,
                              hipStream_t stream)
{
    const int*   inp  = (const int*)d_in[0];    // [1024][256]
    const float* Wk   = (const float*)d_in[1];  // [128][1024]
    const float* R    = (const float*)d_in[2];  // [256][1024]
    const float* bias = (const float*)d_in[3];  // [1024]
    const float* Wd   = (const float*)d_in[4];  // [256][128]
    const float* bd   = (const float*)d_in[5];  // [128]
    float* out = (float*)d_out;

    // ws: R0t|R1t (512KB ea) | Wkb (512KB) | H01A|H01B (1MB ea) | ctr (4KB)
    unsigned short* R0t  = (unsigned short*)d_ws;
    unsigned short* R1t  = R0t + 262144;
    float*          Wkb  = (float*)(R1t + 262144);
    u32*            H01A = (u32*)(Wkb + 131072);
    u32*            H01B = H01A + 262144;
    u32*            ctr  = H01B + 262144;

    prep<<<dim3(1024), dim3(256), 0, stream>>>(R, Wk, bias, R0t, R1t, Wkb, H01A, ctr);

    lstm_persist<<<dim3(128), dim3(256), 0, stream>>>(R0t, R1t, Wkb, inp,
                                                      H01A, H01B, ctr);

    // t=255 output -> parity 0 -> H01A
    dense_softmax<<<dim3(BATCH), dim3(128), 0, stream>>>(H01A, Wd, bd, out);
}

// Round 11
// 1640.494 us; speedup vs baseline: 1.0610x; 1.0610x over previous
//
#include <hip/hip_runtime.h>
#include <math.h>

#define BATCH 1024
#define SEQ   256
#define UNITS 256
#define NC    128

typedef __attribute__((ext_vector_type(8))) short  short8;   // 8 bf16 = 4 regs
typedef __attribute__((ext_vector_type(4))) float  float4v;  // MFMA C/D
typedef unsigned long long u64;
typedef unsigned int       u32;

// Gate math (validated r1-r10: absmax <= 6.1e-5 vs 1.72e-4 threshold)
__device__ __forceinline__ float sigf(float x)  { return 1.f / (1.f + __expf(-x)); }
__device__ __forceinline__ float tanhf_(float x){ return 1.f - 2.f / (1.f + __expf(2.f * x)); }

__device__ __forceinline__ unsigned short bf16rne(float f) {
    unsigned u = __float_as_uint(f);
    return (unsigned short)((u + 0x7fffu + ((u >> 16) & 1u)) >> 16);
}
__device__ __forceinline__ float bf16tof(unsigned short s) {
    return __uint_as_float(((unsigned)s) << 16);
}

// ---------------------------------------------------------------------------
// prep: R0t/R1t[col][k] bf16 split (col = g*256+u, r4-verified layout);
//       Wkb[ch][u*4+g] = Wk + bias (gate-packed); H01A zeroed; ctr zeroed.
__global__ __launch_bounds__(256) void prep(
    const float* __restrict__ R, const float* __restrict__ Wk,
    const float* __restrict__ bias,
    unsigned short* __restrict__ R0t, unsigned short* __restrict__ R1t,
    float* __restrict__ Wkb, u32* __restrict__ H01A, u32* __restrict__ ctr)
{
    int i = blockIdx.x * 256 + threadIdx.x;    // 0..262143
    int col = i >> 8, k = i & 255;
    float v = R[k * 1024 + col];
    unsigned short r0 = bf16rne(v);
    R0t[i] = r0;
    R1t[i] = bf16rne(v - bf16tof(r0));
    H01A[i] = 0u;                              // h_0 = 0 (packed)
    if (i < NC * 1024) {
        int r = i & 1023;
        int u = r >> 2, g = r & 3;
        int src = (g << 8) + u;
        Wkb[i] = Wk[(i >> 10) * 1024 + src] + bias[src];
    }
    if (i < 1024) ctr[i] = 0u;                 // 64 rows x 16-u32 pad
}

// ---------------------------------------------------------------------------
// Persistent LSTM, two-row software pipeline with LATE POLL (r11).
// r10's poll sat ~0.3us into each phase but targeted data published by peers
// at the END of the immediately preceding phase (lockstep => ~0 slack): the
// MALL publish-visibility (~1us) was exposed every phase. r11 moves poll +
// next-row h-loads AFTER the MFMA issue block, so visibility is absorbed by
// the MFMA shadow; the loads drain during the epilogue/publish barrier.
// Grid 128 x 256 thr (1 block/CU). Block = row-pair (2p,2p+1; 16 batches
// each) x 64 units. B-frags in 256 AGPRs (r8-validated inline-asm MFMA),
// 3-product bf16 split (r8-validated margin). Acyclic lockstep -> no
// deadlock; 128 blocks all resident.
__global__ __launch_bounds__(256, 1) void lstm_persist(
    const unsigned short* __restrict__ R0t, const unsigned short* __restrict__ R1t,
    const float* __restrict__ Wkb, const int* __restrict__ inp,
    u32* __restrict__ H01A, u32* __restrict__ H01B, u32* __restrict__ ctr)
{
    __shared__ u32 L[2][2][16 * 132];   // [rowSlot][plane][batch*132+col]

    const int tid  = threadIdx.x;
    const int lane = tid & 63;
    const int wv   = tid >> 6;                  // 0..3
    const int bI   = blockIdx.x;                // 0..127
    const int pr   = bI & 31;                   // pair index (pr%8 == bI%8)
    const int ui   = bI >> 5;                   // 0..3
    const int nl   = lane & 15;
    const int quad = lane >> 4;
    const int u    = ui * 64 + wv * 16 + nl;    // lane's unit
    const int row0 = pr << 1, row1 = row0 | 1;  // two 16-batch rows

    // B-frags (r4-verified layout) -> exactly 256 AGPRs, pinned (r8).
    short8 B0[4][8], B1[4][8];
#pragma unroll
    for (int g = 0; g < 4; g++)
#pragma unroll
        for (int kt = 0; kt < 8; kt++) {
            const int idx = ((g << 8) + u) * 256 + (kt << 5) + (quad << 3);
            B0[g][kt] = *(const short8*)&R0t[idx];
            B1[g][kt] = *(const short8*)&R1t[idx];
        }
#pragma unroll
    for (int g = 0; g < 4; g++)
#pragma unroll
        for (int kt = 0; kt < 8; kt++) {
            asm volatile("" : "+a"(B0[g][kt]));
            asm volatile("" : "+a"(B1[g][kt]));
        }

    float c[2][4] = {{0.f,0.f,0.f,0.f},{0.f,0.f,0.f,0.f}};

    // Preload row0/t=0 h (zeros) from H01A.
    u64 q[8];
    {
        const u64* src = (const u64*)(H01A + (row0 << 12));
#pragma unroll
        for (int i = 0; i < 8; i++)
            q[i] = __hip_atomic_load(src + tid + (i << 8), __ATOMIC_RELAXED,
                                     __HIP_MEMORY_SCOPE_AGENT);
    }

    for (int ph = 0; ph < 2 * SEQ; ph++) {
        const int t    = ph >> 1;
        const int cur  = ph & 1;
        const int rowC = cur ? row1 : row0;
        const int be   = (rowC << 4) + (quad << 2);   // lane's 4-batch base

        // inp + Wkb gathers for (rowC, t): issued at phase top, consumed in
        // the epilogue -> latency hidden by unpack + MFMA.
        int ch[4];
#pragma unroll
        for (int r = 0; r < 4; r++) ch[r] = inp[(be + r) * SEQ + t];
        float4v wk[4];
#pragma unroll
        for (int r = 0; r < 4; r++)
            wk[r] = *(const float4v*)&Wkb[(ch[r] << 10) + (u << 2)];

        // Unpack current row's h (loaded last phase) -> LDS planes.
#pragma unroll
        for (int i = 0; i < 8; i++) {
            const int e = tid + (i << 8);
            u32 w0 = (u32)q[i], w1 = (u32)(q[i] >> 32);
            const int rr = e >> 7, cp = e & 127;
            L[cur][0][rr * 132 + cp] = (w0 & 0xffffu) | (w1 << 16);
            L[cur][1][rr * 132 + cp] = (w0 >> 16) | (w1 & 0xffff0000u);
        }
        __syncthreads();

        // MFMA: A from LDS (shared by 4 waves), B from AGPRs, 3-product
        // split (r8-validated numerics).
        float4v acc[4];
#pragma unroll
        for (int kt = 0; kt < 8; kt++) {
            short8 a0 = *(const short8*)&L[cur][0][nl * 132 + (kt << 4) + (quad << 2)];
            short8 a1 = *(const short8*)&L[cur][1][nl * 132 + (kt << 4) + (quad << 2)];
            if (kt == 0) {
#pragma unroll
                for (int g = 0; g < 4; g++) {
                    asm volatile("v_mfma_f32_16x16x32_bf16 %0, %1, %2, 0"
                                 : "=v"(acc[g]) : "v"(a0), "a"(B0[g][0]));
                    asm volatile("v_mfma_f32_16x16x32_bf16 %0, %1, %2, %0"
                                 : "+v"(acc[g]) : "v"(a1), "a"(B0[g][0]));
                    asm volatile("v_mfma_f32_16x16x32_bf16 %0, %1, %2, %0"
                                 : "+v"(acc[g]) : "v"(a0), "a"(B1[g][0]));
                }
            } else {
#pragma unroll
                for (int g = 0; g < 4; g++) {
                    asm volatile("v_mfma_f32_16x16x32_bf16 %0, %1, %2, %0"
                                 : "+v"(acc[g]) : "v"(a0), "a"(B0[g][kt]));
                    asm volatile("v_mfma_f32_16x16x32_bf16 %0, %1, %2, %0"
                                 : "+v"(acc[g]) : "v"(a1), "a"(B0[g][kt]));
                    asm volatile("v_mfma_f32_16x16x32_bf16 %0, %1, %2, %0"
                                 : "+v"(acc[g]) : "v"(a0), "a"(B1[g][kt]));
                }
            }
        }

        // LATE poll: scheduling fence stops the compiler hoisting the atomic
        // poll/loads above the MFMA block. By now we are ~0.5-1us into the
        // phase, so the peers' end-of-previous-phase publish is visible ->
        // poll succeeds ~immediately; q loads drain during epilogue+barrier.
        asm volatile("" ::: "memory");
        {
            const int rowO = cur ? row0 : row1;
            const int tO   = cur ? t + 1 : t;
            if (tO < SEQ) {
                if (tO > 0) {
                    u32* poc = &ctr[rowO << 4];
                    const u32 target = (u32)(tO << 2);
                    while (__hip_atomic_load(poc, __ATOMIC_RELAXED,
                                             __HIP_MEMORY_SCOPE_AGENT) < target)
                        __builtin_amdgcn_s_sleep(1);
                }
                const u64* src = (const u64*)(((tO & 1) ? H01B : H01A) + (rowO << 12));
#pragma unroll
                for (int i = 0; i < 8; i++)
                    q[i] = __hip_atomic_load(src + tid + (i << 8), __ATOMIC_RELAXED,
                                             __HIP_MEMORY_SCOPE_AGENT);
            }
        }

        // Sound hazard barrier (r10): acc is an operand -> epilogue reads
        // cannot precede it, it cannot precede the MFMAs.
        asm volatile("s_nop 7\n\ts_nop 7\n\ts_nop 7"
                     : "+v"(acc[0]), "+v"(acc[1]), "+v"(acc[2]), "+v"(acc[3]));

        // Epilogue: 4 (batch,unit) states per lane; h out packed u32.
        u32* Hout = (t & 1) ? H01A : H01B;
#pragma unroll
        for (int r = 0; r < 4; r++) {
            float zi = acc[0][r] + wk[r].x;
            float zf = acc[1][r] + wk[r].y;
            float zg = acc[2][r] + wk[r].z;
            float zo = acc[3][r] + wk[r].w;
            float ig = sigf(zi), fg = sigf(zf), gg = tanhf_(zg), og = sigf(zo);
            float cn = fg * c[cur][r] + ig * gg;
            c[cur][r] = cn;
            float hv = og * tanhf_(cn);
            unsigned short h0 = bf16rne(hv);
            unsigned short h1 = bf16rne(hv - bf16tof(h0));
            u32 packed = (u32)h0 | ((u32)h1 << 16);
            __hip_atomic_store(&Hout[(be + r) * 256 + u], packed,
                               __ATOMIC_RELAXED, __HIP_MEMORY_SCOPE_AGENT);
        }

        // Publish: syncthreads drains all waves' vmcnt (h stores + q loads at
        // the coherence point, r8-validated), then one RMW per block.
        if (t != SEQ - 1) {
            __syncthreads();
            if (tid == 0)
                __hip_atomic_fetch_add(&ctr[rowC << 4], 1u, __ATOMIC_RELAXED,
                                       __HIP_MEMORY_SCOPE_AGENT);
        }
    }
}

// ---------------------------------------------------------------------------
// logits = h_last @ dense_w + dense_b ; softmax. h unpacked = lo + hi bf16.
__global__ __launch_bounds__(128) void dense_softmax(
    const u32* __restrict__ H01, const float* __restrict__ W,
    const float* __restrict__ b, float* __restrict__ out)
{
    __shared__ float hsr[UNITS];
    __shared__ float red[NC];
    const int bq = blockIdx.x;
    const int n  = threadIdx.x;

    u32 v0 = H01[bq * 256 + n];
    u32 v1 = H01[bq * 256 + n + 128];
    hsr[n]       = bf16tof((unsigned short)(v0 & 0xffffu)) + bf16tof((unsigned short)(v0 >> 16));
    hsr[n + 128] = bf16tof((unsigned short)(v1 & 0xffffu)) + bf16tof((unsigned short)(v1 >> 16));
    __syncthreads();

    float acc = b[n];
#pragma unroll 8
    for (int k = 0; k < UNITS; k++) acc += hsr[k] * W[k * NC + n];

    red[n] = acc;
    __syncthreads();
    for (int s = 64; s > 0; s >>= 1) {
        if (n < s) red[n] = fmaxf(red[n], red[n + s]);
        __syncthreads();
    }
    float m = red[0];
    __syncthreads();

    float e = __expf(acc - m);
    red[n] = e;
    __syncthreads();
    for (int s = 64; s > 0; s >>= 1) {
        if (n < s) red[n] = red[n] + red[n + s];
        __syncthreads();
    }
    out[bq * NC + n] = e / red[0];
}

// ---------------------------------------------------------------------------
extern "C" void kernel_launch(void* const* d_in, const int* in_sizes, int n_in,
                              void* d_out, int out_size, void* d_ws, size_t ws_size,
                              hipStream_t stream)
{
    const int*   inp  = (const int*)d_in[0];    // [1024][256]
    const float* Wk   = (const float*)d_in[1];  // [128][1024]
    const float* R    = (const float*)d_in[2];  // [256][1024]
    const float* bias = (const float*)d_in[3];  // [1024]
    const float* Wd   = (const float*)d_in[4];  // [256][128]
    const float* bd   = (const float*)d_in[5];  // [128]
    float* out = (float*)d_out;

    // ws: R0t|R1t (512KB ea) | Wkb (512KB) | H01A|H01B (1MB ea) | ctr (4KB)
    unsigned short* R0t  = (unsigned short*)d_ws;
    unsigned short* R1t  = R0t + 262144;
    float*          Wkb  = (float*)(R1t + 262144);
    u32*            H01A = (u32*)(Wkb + 131072);
    u32*            H01B = H01A + 262144;
    u32*            ctr  = H01B + 262144;

    prep<<<dim3(1024), dim3(256), 0, stream>>>(R, Wk, bias, R0t, R1t, Wkb, H01A, ctr);

    lstm_persist<<<dim3(128), dim3(256), 0, stream>>>(R0t, R1t, Wkb, inp,
                                                      H01A, H01B, ctr);

    // t=255 output -> parity 0 -> H01A
    dense_softmax<<<dim3(BATCH), dim3(128), 0, stream>>>(H01A, Wd, bd, out);
}